// Round 1
// baseline (87.334 us; speedup 1.0000x reference)
//
#include <hip/hip_runtime.h>

// Problem: text[SEQ=200, BATCH=4096] int32 token ids in [0, 50000).
// presence[b, v] = 1 iff token v occurs in column b of text.
// out[b] = sum_v presence[b,v] * w[v] + bias  (i.e. sum of w over UNIQUE tokens).
// Output: [4096, 1] float32.

#define SEQ 200
#define BATCH 4096

__global__ __launch_bounds__(256) void MNB_24111946400019_kernel(
    const int* __restrict__ text,
    const float* __restrict__ w,      // [50000]
    const float* __restrict__ bias,   // [1]
    float* __restrict__ out)          // [4096]
{
    __shared__ int toks[SEQ];
    __shared__ float partial[4];

    const int b = blockIdx.x;   // batch column
    const int t = threadIdx.x;

    // Stage this column's 200 tokens into LDS.
    // text is [seq, batch] row-major: element (s, b) at s*BATCH + b.
    if (t < SEQ) toks[t] = text[t * BATCH + b];
    __syncthreads();

    // Thread t owns position t: contributes w[tok] only if this is the FIRST
    // occurrence of tok in the column (duplicates collapse to presence=1).
    float sum = 0.0f;
    if (t < SEQ) {
        const int tok = toks[t];
        bool first = true;
        for (int i = 0; i < t; ++i) {
            if (toks[i] == tok) { first = false; break; }
        }
        if (first) sum = w[tok];
    }

    // Wave (64-lane) shuffle reduction, then LDS across the 4 waves.
    #pragma unroll
    for (int off = 32; off > 0; off >>= 1)
        sum += __shfl_down(sum, off, 64);

    const int wave = t >> 6;
    const int lane = t & 63;
    if (lane == 0) partial[wave] = sum;
    __syncthreads();

    if (t == 0) {
        float s = partial[0] + partial[1] + partial[2] + partial[3];
        out[b] = s + bias[0];
    }
}

extern "C" void kernel_launch(void* const* d_in, const int* in_sizes, int n_in,
                              void* d_out, int out_size, void* d_ws, size_t ws_size,
                              hipStream_t stream) {
    const int*   text = (const int*)d_in[0];    // [200*4096]
    const float* w    = (const float*)d_in[1];  // [50000]
    const float* bias = (const float*)d_in[2];  // [1]
    float* out = (float*)d_out;                 // [4096]

    MNB_24111946400019_kernel<<<BATCH, 256, 0, stream>>>(text, w, bias, out);
}

// Round 2
// 66.313 us; speedup vs baseline: 1.3170x; 1.3170x over previous
//
#include <hip/hip_runtime.h>

// Problem: text[SEQ=200, BATCH=4096] int32 token ids in [0, 50000).
// out[b] = bias + sum of w[tok] over the UNIQUE tokens in column b.
//
// R2: O(SEQ) LDS hash-set dedup (atomicCAS open addressing) instead of the
// R1 O(SEQ^2) serial first-occurrence scan whose dependent ds_read chain
// dominated runtime.

#define SEQ 200
#define BATCH 4096
#define TABLE 512   // power of 2, > 2*SEQ so load factor < 0.4

__global__ __launch_bounds__(256) void MNB_24111946400019_kernel(
    const int* __restrict__ text,
    const float* __restrict__ w,      // [50000]
    const float* __restrict__ bias,   // [1]
    float* __restrict__ out)          // [4096]
{
    __shared__ int table[TABLE];
    __shared__ float partial[4];

    const int b = blockIdx.x;   // batch column
    const int t = threadIdx.x;

    // Init hash table to empty (-1). 256 threads x 2 slots.
    table[t] = -1;
    table[t + 256] = -1;
    __syncthreads();

    float sum = 0.0f;
    if (t < SEQ) {
        const int tok = text[t * BATCH + b];
        // Fibonacci-multiply hash -> 9 bits.
        unsigned h = ((unsigned)tok * 2654435761u) >> 23;
        // Concurrent open-addressing insert. Slot transitions -1 -> tok
        // exactly once; the CAS winner (prev == -1) owns the contribution.
        for (;;) {
            int prev = atomicCAS(&table[h], -1, tok);
            if (prev == -1) { sum = w[tok]; break; }  // first occurrence
            if (prev == tok) break;                    // duplicate
            h = (h + 1) & (TABLE - 1);                 // collision: probe
        }
    }

    // Wave (64-lane) shuffle reduction, then LDS across the 4 waves.
    #pragma unroll
    for (int off = 32; off > 0; off >>= 1)
        sum += __shfl_down(sum, off, 64);

    const int wave = t >> 6;
    const int lane = t & 63;
    if (lane == 0) partial[wave] = sum;
    __syncthreads();

    if (t == 0) {
        out[b] = partial[0] + partial[1] + partial[2] + partial[3] + bias[0];
    }
}

extern "C" void kernel_launch(void* const* d_in, const int* in_sizes, int n_in,
                              void* d_out, int out_size, void* d_ws, size_t ws_size,
                              hipStream_t stream) {
    const int*   text = (const int*)d_in[0];    // [200*4096]
    const float* w    = (const float*)d_in[1];  // [50000]
    const float* bias = (const float*)d_in[2];  // [1]
    float* out = (float*)d_out;                 // [4096]

    MNB_24111946400019_kernel<<<BATCH, 256, 0, stream>>>(text, w, bias, out);
}

// Round 3
// 65.438 us; speedup vs baseline: 1.3346x; 1.0134x over previous
//
#include <hip/hip_runtime.h>

// out[b] = bias + sum of w[tok] over UNIQUE tokens in column b of
// text[SEQ=200, BATCH=4096].
//
// R3: 8 columns per block. (1) Coalesced-ish staging of text into LDS
// (8 lines/wave-load vs 64 scattered). (2) CAS hash insert does dedup ONLY
// (no dependent w-gather in the probe loop). (3) Separate slot-scan phase
// gathers w with independent loads + conflict-free LDS reads, then a
// 32-lane shuffle reduction per column.

#define SEQ    200
#define BATCH  4096
#define COLS   8              // columns per block
#define TSLOTS 512            // hash slots per column (load factor ~0.39)
#define NTOK   (SEQ * COLS)   // 1600 staged tokens per block

__global__ __launch_bounds__(256) void MNB_24111946400019_kernel(
    const int* __restrict__ text,
    const float* __restrict__ w,      // [50000]
    const float* __restrict__ bias,   // [1]
    float* __restrict__ out)          // [4096]
{
    __shared__ int staged[NTOK];            // 6.4 KB
    __shared__ int table[COLS * TSLOTS];    // 16 KB

    const int t  = threadIdx.x;
    const int c0 = blockIdx.x * COLS;

    // Init tables: 4096 slots / 256 threads = 16 each, via 4x int4 stores.
    {
        const int4 m1 = make_int4(-1, -1, -1, -1);
        int4* tb = (int4*)table;
        #pragma unroll
        for (int i = 0; i < 4; ++i) tb[t + 256 * i] = m1;
    }

    // Stage tokens. idx = s*COLS + j -> consecutive lanes cover 8 cols x 8
    // rows per wave-load: 8 line transactions instead of 64.
    for (int idx = t; idx < NTOK; idx += 256) {
        const int s = idx >> 3;          // seq position
        const int j = idx & (COLS - 1);  // column within block
        staged[idx] = text[s * BATCH + c0 + j];
    }
    __syncthreads();

    // Dedup via open-addressing CAS insert. No w load here.
    for (int idx = t; idx < NTOK; idx += 256) {
        const int tok = staged[idx];
        const int j   = idx & (COLS - 1);
        unsigned h = ((unsigned)tok * 2654435761u) >> 23;  // 9-bit hash
        int* tb = &table[j * TSLOTS];
        for (;;) {
            const int prev = atomicCAS(&tb[h], -1, tok);
            if (prev == -1 || prev == tok) break;
            h = (h + 1) & (TSLOTS - 1);
        }
    }
    __syncthreads();

    // Slot scan + gather: 32 threads per column, 16 slots each.
    // LDS addr = j*512 + l + 32k -> bank = l (conflict-free; the two wave
    // halves alias 2-way which is free).
    const int j = t >> 5;   // column 0..7
    const int l = t & 31;
    float sum = 0.0f;
    #pragma unroll
    for (int k = 0; k < TSLOTS / 32; ++k) {
        const int tok = table[j * TSLOTS + l + 32 * k];
        if (tok >= 0) sum += w[tok];   // independent scattered L2 gathers
    }

    // Reduce across the 32 lanes of each half-wave (xor with off<32 stays
    // within the 32-lane half on wave64).
    #pragma unroll
    for (int off = 16; off > 0; off >>= 1)
        sum += __shfl_xor(sum, off, 64);

    if (l == 0) out[c0 + j] = sum + bias[0];
}

extern "C" void kernel_launch(void* const* d_in, const int* in_sizes, int n_in,
                              void* d_out, int out_size, void* d_ws, size_t ws_size,
                              hipStream_t stream) {
    const int*   text = (const int*)d_in[0];    // [200*4096]
    const float* w    = (const float*)d_in[1];  // [50000]
    const float* bias = (const float*)d_in[2];  // [1]
    float* out = (float*)d_out;                 // [4096]

    MNB_24111946400019_kernel<<<BATCH / COLS, 256, 0, stream>>>(text, w, bias, out);
}